// Round 4
// baseline (550.021 us; speedup 1.0000x reference)
//
#include <hip/hip_runtime.h>
#include <math.h>

#define NB 2
#define HB 8
#define LB 2048
#define EB 64
#define BITSN 32
#define CLN 128
#define ITERS 10
#define TOPKN 32
#define NEGV -10000000.0f

typedef unsigned long long u64;
typedef unsigned int u32;

// ---------------------------------------------------------------------------
// Kernel 1: LSH bits. One wave handles 2 queries; lane = 32*which + b.
// ---------------------------------------------------------------------------
__global__ __launch_bounds__(256) void bits_kernel(const float* __restrict__ q,
                                                   const float* __restrict__ planes,
                                                   u32* __restrict__ bits) {
    int tid = threadIdx.x;
    int wave = tid >> 6;
    int lane = tid & 63;
    int b = lane & 31;
    int which = lane >> 5;
    int qi = blockIdx.x * 8 + wave * 2 + which;   // qi = (n*H + h)*L + l
    int l = qi & (LB - 1);
    int nh = qi / LB;
    int h = nh & (HB - 1);
    int n = nh / HB;
    const float* qrow = q + (((long long)n * LB + l) * HB + h) * EB;
    const float* prow = planes + b * (EB + 1);
    double acc = (double)prow[EB];                 // bias (the ones column)
    #pragma unroll 8
    for (int e = 0; e < EB; ++e) acc += (double)qrow[e] * (double)prow[e];
    unsigned long long m = __ballot(acc > 0.0);
    if (b == 0) {
        bits[qi] = (u32)(which ? (m >> 32) : (m & 0xffffffffULL));
    }
}

// ---------------------------------------------------------------------------
// Kernel 2: k-means on Hamming distance. One block (1024 thr) per (n,h).
// All integer / exact; argmin = first min; centroid bit: 2*sums >= cnt.
// Restructured: readlane-cached centroids (no LDS in argmin loop),
// ballot-based histogram (no per-bit atomics), exact convergence early-exit,
// deterministic ballot-rank member-list emission (ascending l).
// ---------------------------------------------------------------------------
__global__ __launch_bounds__(1024) void cluster_kernel(const u32* __restrict__ bits,
                                                       int* __restrict__ assign_g,
                                                       int* __restrict__ cnt_g,
                                                       int* __restrict__ ofs_g,
                                                       int* __restrict__ list_g) {
    __shared__ u32 bl[LB];                 // 8 KB
    __shared__ u32 cent[CLN];
    __shared__ int sums[CLN * BITSN];      // 16 KB
    __shared__ int cnt[CLN];
    __shared__ int cntw[2][16][CLN];       // 16 KB: (group, wave, cluster)
    __shared__ int ofs[CLN];
    __shared__ int changed;

    int nh = blockIdx.x;
    int tid = threadIdx.x;
    int w = tid >> 6, lane = tid & 63;
    int l0 = tid;              // group-0 point
    int l1 = tid + 1024;       // group-1 point

    for (int l = tid; l < LB; l += 1024) bl[l] = bits[nh * LB + l];
    __syncthreads();
    if (tid < CLN) cent[tid] = bl[tid * (LB / CLN)];   // init_idx = 16c
    __syncthreads();

    u32 bv0 = bl[l0], bv1 = bl[l1];

    // per-wave transposed bit masks: lane j<32 holds ballot of bit j (both groups)
    u64 bT0 = 0ULL, bT1 = 0ULL;
    for (int j = 0; j < 32; ++j) {
        u64 t0 = __ballot((bv0 >> j) & 1u);
        u64 t1 = __ballot((bv1 >> j) & 1u);
        if (lane == j) { bT0 = t0; bT1 = t1; }
    }
    u64 ltmask = (lane == 0) ? 0ULL : (~0ULL >> (64 - lane));

    int old0 = -1, old1 = -1;
    int bc0 = 0, bc1 = 0;

    for (int it = 0; it < ITERS; ++it) {
        for (int i = tid; i < CLN * BITSN; i += 1024) sums[i] = 0;
        if (tid < CLN) cnt[tid] = 0;
        if (tid == 0) changed = 0;
        __syncthreads();

        // ---- assignment: pure-VALU argmin via readlane-cached centroids
        u32 clo = cent[lane], chi = cent[lane + 64];
        int best0 = 99, best1 = 99;
        bc0 = 0; bc1 = 0;
        #pragma unroll 16
        for (int c = 0; c < 64; ++c) {
            u32 cc = (u32)__builtin_amdgcn_readlane((int)clo, c);
            int d0 = __popc(bv0 ^ cc); if (d0 < best0) { best0 = d0; bc0 = c; }
            int d1 = __popc(bv1 ^ cc); if (d1 < best1) { best1 = d1; bc1 = c; }
        }
        #pragma unroll 16
        for (int c = 0; c < 64; ++c) {
            u32 cc = (u32)__builtin_amdgcn_readlane((int)chi, c);
            int d0 = __popc(bv0 ^ cc); if (d0 < best0) { best0 = d0; bc0 = 64 + c; }
            int d1 = __popc(bv1 ^ cc); if (d1 < best1) { best1 = d1; bc1 = 64 + c; }
        }
        if (bc0 != old0 || bc1 != old1) changed = 1;   // race-benign (all write 1)
        old0 = bc0; old1 = bc1;

        // ---- histogram via ballots: one 32-lane ds_add per active (wave, c)
        for (int c = 0; c < CLN; ++c) {
            u64 m0 = __ballot(bc0 == c);
            u64 m1 = __ballot(bc1 == c);
            if ((m0 | m1) == 0ULL) continue;           // wave-uniform skip
            if (lane < 32) {
                int v = __popcll(m0 & bT0) + __popcll(m1 & bT1);
                if (v) atomicAdd(&sums[c * BITSN + lane], v);
            } else if (lane == 32) {
                atomicAdd(&cnt[c], __popcll(m0) + __popcll(m1));
            }
        }
        __syncthreads();
        if (!changed) break;    // converged: all remaining iterations are identity

        // ---- centroid update (exact integer compare)
        if (tid < CLN) {
            int c = tid, cn = cnt[c];
            if (cn > 0) {
                u32 nb = 0u;
                for (int j = 0; j < BITSN; ++j)
                    if (2 * sums[c * BITSN + j] >= cn) nb |= (1u << j);
                cent[c] = nb;
            }
        }
        __syncthreads();
    }

    // ---- final assignment pass (reference's 11th distance computation)
    if (tid < CLN) cnt[tid] = 0;
    for (int i = tid; i < 2 * 16 * CLN; i += 1024) (&cntw[0][0][0])[i] = 0;
    __syncthreads();
    {
        u32 clo = cent[lane], chi = cent[lane + 64];
        int best0 = 99, best1 = 99;
        bc0 = 0; bc1 = 0;
        #pragma unroll 16
        for (int c = 0; c < 64; ++c) {
            u32 cc = (u32)__builtin_amdgcn_readlane((int)clo, c);
            int d0 = __popc(bv0 ^ cc); if (d0 < best0) { best0 = d0; bc0 = c; }
            int d1 = __popc(bv1 ^ cc); if (d1 < best1) { best1 = d1; bc1 = c; }
        }
        #pragma unroll 16
        for (int c = 0; c < 64; ++c) {
            u32 cc = (u32)__builtin_amdgcn_readlane((int)chi, c);
            int d0 = __popc(bv0 ^ cc); if (d0 < best0) { best0 = d0; bc0 = 64 + c; }
            int d1 = __popc(bv1 ^ cc); if (d1 < best1) { best1 = d1; bc1 = 64 + c; }
        }
    }
    assign_g[nh * LB + l0] = bc0;
    assign_g[nh * LB + l1] = bc1;

    // counts + per-(group,wave) counts + within-wave ranks (deterministic)
    int rank0 = 0, rank1 = 0;
    for (int c = 0; c < CLN; ++c) {
        u64 m0 = __ballot(bc0 == c);
        u64 m1 = __ballot(bc1 == c);
        if ((m0 | m1) == 0ULL) continue;
        if (bc0 == c) rank0 = (int)__popcll(m0 & ltmask);
        if (bc1 == c) rank1 = (int)__popcll(m1 & ltmask);
        if (lane == 0) {
            int p0 = (int)__popcll(m0), p1 = (int)__popcll(m1);
            if (p0) cntw[0][w][c] = p0;
            if (p1) cntw[1][w][c] = p1;
            atomicAdd(&cnt[c], p0 + p1);
        }
    }
    __syncthreads();
    if (tid == 0) {            // block exclusive prefix over c (once, cheap)
        int run = 0;
        for (int c = 0; c < CLN; ++c) { ofs[c] = run; run += cnt[c]; }
    }
    __syncthreads();
    if (tid < CLN) {           // absolute bases per (g,w) in ascending-l order
        int c = tid;
        int run = ofs[c];
        #pragma unroll
        for (int g = 0; g < 2; ++g)
            for (int ww = 0; ww < 16; ++ww) {
                int t = cntw[g][ww][c];
                cntw[g][ww][c] = run;
                run += t;
            }
        cnt_g[nh * CLN + c] = cnt[c];
        ofs_g[nh * CLN + c] = ofs[c];
    }
    __syncthreads();
    list_g[nh * LB + cntw[0][w][bc0] + rank0] = l0;
    list_g[nh * LB + cntw[1][w][bc1] + rank1] = l1;
}

// ---------------------------------------------------------------------------
// Kernel 3a: Qg per (n,h,c) via member list. f64 ascending-l sum, stored f32.
// ---------------------------------------------------------------------------
__global__ __launch_bounds__(64) void qg_kernel(const float* __restrict__ q,
                                                const int* __restrict__ cnt_g,
                                                const int* __restrict__ ofs_g,
                                                const int* __restrict__ list_g,
                                                float* __restrict__ qgf) {
    int bid = blockIdx.x;            // nh*128 + c
    int nh = bid >> 7;
    int h = nh & (HB - 1);
    int n = nh / HB;
    int e = threadIdx.x;
    int cn = cnt_g[bid];
    int o = ofs_g[bid];
    const int* lp = list_g + nh * LB + o;
    double acc = 0.0;
    for (int i = 0; i < cn; ++i) {
        int l = lp[i];
        acc += (double)q[(((long long)n * LB + l) * HB + h) * EB + e];
    }
    double dcn = (double)(cn > 0 ? cn : 1);
    qgf[(long long)bid * EB + e] = (float)(acc / dcn);
}

// ---------------------------------------------------------------------------
// Kernel 3b: scores. Block per (nh, 128-row tile) -> K read exactly once.
// ---------------------------------------------------------------------------
__global__ __launch_bounds__(256) void scores_kernel(const float* __restrict__ kk,
                                                     const float* __restrict__ qgf,
                                                     u32* __restrict__ keys) {
    int bid = blockIdx.x;            // nh*16 + tile
    int nh = bid >> 4;
    int tile = bid & 15;
    int h = nh & (HB - 1);
    int n = nh / HB;
    int w = threadIdx.x >> 6;
    int lane = threadIdx.x & 63;
    int rl = (w & 1) * 64 + lane;    // row within tile
    int l = tile * 128 + rl;
    int cbase = (w >> 1) * 64;       // waves 0,1: c 0-63; waves 2,3: c 64-127

    const float4* kr4 = (const float4*)(kk + (((long long)n * LB + l) * HB + h) * EB);
    float rr[EB];
    #pragma unroll
    for (int i = 0; i < 16; ++i) {
        float4 t4 = kr4[i];
        rr[4 * i] = t4.x; rr[4 * i + 1] = t4.y; rr[4 * i + 2] = t4.z; rr[4 * i + 3] = t4.w;
    }
    const float* qp0 = qgf + ((long long)nh * CLN + cbase) * EB;
    for (int c = 0; c < 64; ++c) {
        const float4* qp = (const float4*)(qp0 + c * EB);   // wave-uniform address
        float acc = 0.f;
        #pragma unroll
        for (int i = 0; i < 16; ++i) {
            float4 qv = qp[i];
            acc = fmaf(qv.x, rr[4 * i], acc);
            acc = fmaf(qv.y, rr[4 * i + 1], acc);
            acc = fmaf(qv.z, rr[4 * i + 2], acc);
            acc = fmaf(qv.w, rr[4 * i + 3], acc);
        }
        u32 u = __float_as_uint(acc);
        u = ((int)u < 0) ? ~u : (u | 0x80000000u);          // monotone f32->u32
        keys[((long long)(nh * CLN + cbase + c)) * LB + l] = u;
    }
}

// ---------------------------------------------------------------------------
// Kernel 3c: top-32 per (n,h,c). One wave; keys packed (key<<32)|(2047-l).
// ---------------------------------------------------------------------------
__global__ __launch_bounds__(64) void topsel_kernel(const u32* __restrict__ keys,
                                                    int* __restrict__ tki) {
    int bid = blockIdx.x;            // nh*128 + c
    int lane = threadIdx.x;
    const uint4* kp4 = (const uint4*)(keys + (long long)bid * LB);
    u64 k[32];
    #pragma unroll
    for (int t = 0; t < 8; ++t) {
        uint4 kv = kp4[lane + 64 * t];
        int l0 = (lane + 64 * t) * 4;
        k[4 * t]     = ((u64)kv.x << 32) | (u32)(2047 - l0);
        k[4 * t + 1] = ((u64)kv.y << 32) | (u32)(2047 - (l0 + 1));
        k[4 * t + 2] = ((u64)kv.z << 32) | (u32)(2047 - (l0 + 2));
        k[4 * t + 3] = ((u64)kv.w << 32) | (u32)(2047 - (l0 + 3));
    }
    u64 m0 = k[0], m1 = k[8], m2 = k[16], m3 = k[24];
    #pragma unroll
    for (int t = 1; t < 8; ++t) {
        if (k[t] > m0) m0 = k[t];
        if (k[8 + t] > m1) m1 = k[8 + t];
        if (k[16 + t] > m2) m2 = k[16 + t];
        if (k[24 + t] > m3) m3 = k[24 + t];
    }
    if (m1 > m0) m0 = m1;
    if (m3 > m2) m2 = m3;
    u64 cur = (m2 > m0) ? m2 : m0;

    for (int r = 0; r < TOPKN; ++r) {
        u64 wk = cur;
        #pragma unroll
        for (int off = 1; off < 64; off <<= 1) {
            u64 o = __shfl_xor(wk, off);
            if (o > wk) wk = o;
        }
        if (lane == 0) tki[bid * TOPKN + r] = 2047 - (int)(wk & 2047u);
        if (wk == cur) {               // unique owner (indices embedded)
            u64 nm = 0ULL;
            #pragma unroll
            for (int t = 0; t < 32; ++t) {
                u64 kt = k[t];
                u64 cand = (kt < wk) ? kt : 0ULL;
                if (cand > nm) nm = cand;
            }
            cur = nm;
        }
    }
}

// ---------------------------------------------------------------------------
// Kernel 4: gather attention. One wave per query (n,h,l).
// ---------------------------------------------------------------------------
__global__ __launch_bounds__(256) void attn_kernel(const float* __restrict__ q,
                                                   const float* __restrict__ kk,
                                                   const float* __restrict__ vv,
                                                   const int* __restrict__ assign_g,
                                                   const int* __restrict__ tki,
                                                   float* __restrict__ out) {
    int tid = threadIdx.x;
    int wave = tid >> 6, lane = tid & 63;
    int qi = blockIdx.x * 4 + wave;   // (nh)*L + l
    int l = qi & (LB - 1);
    int nh = qi / LB;
    int h = nh & (HB - 1);
    int n = nh / HB;
    int c = assign_g[qi];
    const int* krow = tki + (nh * CLN + c) * TOPKN;
    int j = lane & 31, p = lane >> 5;
    int kidx = krow[j];

    const float4* q4 = (const float4*)(q + (((long long)n * LB + l) * HB + h) * EB) + p * 8;
    const float4* k4 = (const float4*)(kk + (((long long)n * LB + kidx) * HB + h) * EB) + p * 8;
    float part = 0.f;
    #pragma unroll
    for (int i = 0; i < 8; ++i) {
        float4 a = q4[i], b = k4[i];
        part += a.x * b.x + a.y * b.y + a.z * b.z + a.w * b.w;
    }
    float qlo = __shfl(part, j);
    float qhi = __shfl(part, j + 32);
    float qk = qlo + qhi;

    bool future = kidx > l;
    float logit = 0.125f * (future ? NEGV : qk);
    float m = logit;
    #pragma unroll
    for (int off = 16; off; off >>= 1) m = fmaxf(m, __shfl_xor(m, off));
    float ex = expf(logit - m);
    float ssum = ex;
    #pragma unroll
    for (int off = 16; off; off >>= 1) ssum += __shfl_xor(ssum, off);
    float a = future ? 0.f : ex / ssum;

    const float* vbase = vv + ((long long)n * LB * HB + h) * EB;  // + ki*H*E + e
    float oacc = 0.f;
    #pragma unroll 4
    for (int jj = 0; jj < TOPKN; ++jj) {
        float aj = __shfl(a, jj);
        int kj = __shfl(kidx, jj);
        if (aj != 0.f)   // wave-uniform
            oacc += aj * vbase[(long long)kj * (HB * EB) + lane];
    }
    out[(((long long)n * LB + l) * HB + h) * EB + lane] = oacc;
}

// ---------------------------------------------------------------------------
extern "C" void kernel_launch(void* const* d_in, const int* in_sizes, int n_in,
                              void* d_out, int out_size, void* d_ws, size_t ws_size,
                              hipStream_t stream) {
    const float* q = (const float*)d_in[0];
    const float* k = (const float*)d_in[1];
    const float* v = (const float*)d_in[2];
    const float* planes = (const float*)d_in[3];
    float* out = (float*)d_out;

    const int NQ = NB * HB * LB;                  // 32768
    char* ws = (char*)d_ws;
    u32* bits     = (u32*)(ws);                    // 128 KB
    int* assign_g = (int*)(ws + 0x20000);          // 128 KB
    int* cnt_g    = (int*)(ws + 0x40000);          // 8 KB
    int* ofs_g    = (int*)(ws + 0x42000);          // 8 KB
    int* list_g   = (int*)(ws + 0x44000);          // 128 KB
    float* qgf    = (float*)(ws + 0x64000);        // 512 KB
    int* tki      = (int*)(ws + 0xE4000);          // 256 KB
    u32* keys     = (u32*)(ws + 0x124000);         // 16 MB

    bits_kernel<<<NQ / 8, 256, 0, stream>>>(q, planes, bits);
    cluster_kernel<<<NB * HB, 1024, 0, stream>>>(bits, assign_g, cnt_g, ofs_g, list_g);
    qg_kernel<<<NB * HB * CLN, 64, 0, stream>>>(q, cnt_g, ofs_g, list_g, qgf);
    scores_kernel<<<NB * HB * 16, 256, 0, stream>>>(k, qgf, keys);
    topsel_kernel<<<NB * HB * CLN, 64, 0, stream>>>(keys, tki);
    attn_kernel<<<NQ / 4, 256, 0, stream>>>(q, k, v, assign_g, tki, out);
}